// Round 1
// baseline (568.912 us; speedup 1.0000x reference)
//
#include <hip/hip_runtime.h>

#define B_ 128
#define T_ 1000
#define I_ 3
#define H_ 512
#define NOISE_STD 0.05f
#define ALPHA 0.2f

// DPP-based add of a lane-shifted copy: x += dpp_mov(x, CTRL).
// CTRL: row_shr:N = 0x110|N, row_bcast:15 = 0x142, row_bcast:31 = 0x143.
template <int CTRL>
__device__ __forceinline__ float dpp_add(float x) {
    int moved = __builtin_amdgcn_update_dpp(0, __float_as_int(x), CTRL, 0xf, 0xf, true);
    return x + __int_as_float(moved);
}

// Full wave64 sum of 3 values simultaneously (interleaved for ILP).
// Result valid in lane 63 of the wave.
__device__ __forceinline__ void wave_reduce3(float& p0, float& p1, float& p2) {
    p0 = dpp_add<0x111>(p0); p1 = dpp_add<0x111>(p1); p2 = dpp_add<0x111>(p2);
    p0 = dpp_add<0x112>(p0); p1 = dpp_add<0x112>(p1); p2 = dpp_add<0x112>(p2);
    p0 = dpp_add<0x114>(p0); p1 = dpp_add<0x114>(p1); p2 = dpp_add<0x114>(p2);
    p0 = dpp_add<0x118>(p0); p1 = dpp_add<0x118>(p1); p2 = dpp_add<0x118>(p2);
    p0 = dpp_add<0x142>(p0); p1 = dpp_add<0x142>(p1); p2 = dpp_add<0x142>(p2);
    p0 = dpp_add<0x143>(p0); p1 = dpp_add<0x143>(p1); p2 = dpp_add<0x143>(p2);
}

__global__ __launch_bounds__(512) void lowrank_rnn_kernel(
    const float* __restrict__ input,   // (B,T,I)
    const float* __restrict__ noise,   // (B,T,H)
    const float* __restrict__ wi,      // (I,H)
    const float* __restrict__ si,      // (I,)
    const float* __restrict__ m,       // (H,R)
    const float* __restrict__ n,       // (H,R)
    const float* __restrict__ wo,      // (H,O=1)
    const float* __restrict__ so,      // (1,)
    const float* __restrict__ h0,      // (H,)
    float* __restrict__ out)           // [output (B,T,1) | traj (B,T+1,H)]
{
    const int b    = blockIdx.x;
    const int j    = threadIdx.x;      // hidden index
    const int wave = j >> 6;
    const int lane = j & 63;

    __shared__ float  xs[T_ * I_];     // 12 KB: this batch's input sequence
    __shared__ float4 part[2][8];      // double-buffered per-wave partials

    // Stage x[b] into LDS (coalesced).
    for (int idx = j; idx < T_ * I_; idx += H_)
        xs[idx] = input[(size_t)b * T_ * I_ + idx];

    // Per-thread constants.
    float h   = h0[j];
    float n0v = n[2 * j], n1v = n[2 * j + 1];
    float m0v = m[2 * j], m1v = m[2 * j + 1];
    float wof = wo[j] * so[0];
    float w0  = si[0] * wi[j];
    float w1  = si[1] * wi[H_ + j];
    float w2  = si[2] * wi[2 * H_ + j];

    const float* zp    = noise + (size_t)b * T_ * H_ + j;
    float*       outp  = out + (size_t)b * T_;
    float*       trajp = out + (size_t)B_ * T_ + (size_t)b * (T_ + 1) * H_ + j;

    trajp[0] = h;  // trajectories[:,0,:] = h0

    // 3-deep noise prefetch pipeline (HBM latency ~900cyc > per-step work).
    float z0 = zp[0];
    float z1 = zp[(size_t)1 * H_];
    float z2 = zp[(size_t)2 * H_];

    __syncthreads();  // xs ready

    float x0 = xs[0], x1 = xs[1], x2 = xs[2];

    #pragma unroll 2
    for (int t = 0; t < T_; ++t) {
        float r  = tanhf(h);
        float p0 = r * n0v, p1 = r * n1v, p2 = r * wof;
        wave_reduce3(p0, p1, p2);
        if (lane == 63) part[t & 1][wave] = make_float4(p0, p1, p2, 0.f);

        // Off-critical-path work while reduction partials settle.
        float xw   = x0 * w0 + x1 * w1 + x2 * w2;
        float base = 0.8f * h + NOISE_STD * z0 + ALPHA * xw;

        // Shift prefetch pipeline (clamped index: branch-free, tail re-reads last).
        z0 = z1; z1 = z2;
        int tz = (t + 3 < T_) ? (t + 3) : (T_ - 1);
        z2 = zp[(size_t)tz * H_];
        int tx = (t + 1 < T_) ? (t + 1) : (T_ - 1);
        x0 = xs[tx * 3]; x1 = xs[tx * 3 + 1]; x2 = xs[tx * 3 + 2];

        __syncthreads();  // partials visible (double-buffered: 1 barrier/step)

        float4 q0 = part[t & 1][0], q1 = part[t & 1][1];
        float4 q2 = part[t & 1][2], q3 = part[t & 1][3];
        float4 q4 = part[t & 1][4], q5 = part[t & 1][5];
        float4 q6 = part[t & 1][6], q7 = part[t & 1][7];
        float a0 = ((q0.x + q1.x) + (q2.x + q3.x)) + ((q4.x + q5.x) + (q6.x + q7.x));
        float a1 = ((q0.y + q1.y) + (q2.y + q3.y)) + ((q4.y + q5.y) + (q6.y + q7.y));
        float o  = ((q0.z + q1.z) + (q2.z + q3.z)) + ((q4.z + q5.z) + (q6.z + q7.z));

        // out_{t-1} = tanh(h_t)·wo_full  (r of this step)
        if (t > 0 && j == 0) outp[t - 1] = o;

        h = base + ALPHA * (a0 * m0v + a1 * m1v);
        trajp[(size_t)(t + 1) * H_] = h;
    }

    // Final output: out_{T-1} = tanh(h_T)·wo_full
    {
        float r  = tanhf(h);
        float p2 = r * wof;
        p2 = dpp_add<0x111>(p2); p2 = dpp_add<0x112>(p2);
        p2 = dpp_add<0x114>(p2); p2 = dpp_add<0x118>(p2);
        p2 = dpp_add<0x142>(p2); p2 = dpp_add<0x143>(p2);
        if (lane == 63) part[0][wave] = make_float4(0.f, 0.f, p2, 0.f);
        __syncthreads();
        if (j == 0) {
            float o = 0.f;
            for (int w = 0; w < 8; ++w) o += part[0][w].z;
            outp[T_ - 1] = o;
        }
    }
}

extern "C" void kernel_launch(void* const* d_in, const int* in_sizes, int n_in,
                              void* d_out, int out_size, void* d_ws, size_t ws_size,
                              hipStream_t stream) {
    const float* input = (const float*)d_in[0];
    const float* noise = (const float*)d_in[1];
    const float* wi    = (const float*)d_in[2];
    const float* si    = (const float*)d_in[3];
    const float* m     = (const float*)d_in[4];
    const float* n     = (const float*)d_in[5];
    const float* wo    = (const float*)d_in[6];
    const float* so    = (const float*)d_in[7];
    const float* h0    = (const float*)d_in[8];
    float* out = (float*)d_out;

    hipLaunchKernelGGL(lowrank_rnn_kernel, dim3(B_), dim3(H_), 0, stream,
                       input, noise, wi, si, m, n, wo, so, h0, out);
}

// Round 2
// 492.378 us; speedup vs baseline: 1.1554x; 1.1554x over previous
//
#include <hip/hip_runtime.h>

#define B_ 128
#define T_ 1000
#define I_ 3
#define H_ 512
#define NOISE_STD 0.05f
#define ALPHA 0.2f

// DPP-based add of a lane-shifted copy: x += dpp_mov(x, CTRL).
// CTRL: row_shr:N = 0x110|N, row_bcast:15 = 0x142, row_bcast:31 = 0x143.
template <int CTRL>
__device__ __forceinline__ float dpp_add(float x) {
    int moved = __builtin_amdgcn_update_dpp(0, __float_as_int(x), CTRL, 0xf, 0xf, true);
    return x + __int_as_float(moved);
}

// Full wave64 sum of 3 values simultaneously (interleaved for ILP).
// Result valid in lane 63 of the wave.
__device__ __forceinline__ void wave_reduce3(float& p0, float& p1, float& p2) {
    p0 = dpp_add<0x111>(p0); p1 = dpp_add<0x111>(p1); p2 = dpp_add<0x111>(p2);
    p0 = dpp_add<0x112>(p0); p1 = dpp_add<0x112>(p1); p2 = dpp_add<0x112>(p2);
    p0 = dpp_add<0x114>(p0); p1 = dpp_add<0x114>(p1); p2 = dpp_add<0x114>(p2);
    p0 = dpp_add<0x118>(p0); p1 = dpp_add<0x118>(p1); p2 = dpp_add<0x118>(p2);
    p0 = dpp_add<0x142>(p0); p1 = dpp_add<0x142>(p1); p2 = dpp_add<0x142>(p2);
    p0 = dpp_add<0x143>(p0); p1 = dpp_add<0x143>(p1); p2 = dpp_add<0x143>(p2);
}

// Lightweight block barrier: LDS visibility only. Unlike __syncthreads(),
// does NOT drain vmcnt — global prefetch loads / streamed stores stay in
// flight across the barrier (this was the ~1100 cyc/step stall).
__device__ __forceinline__ void barrier_lds_only() {
    asm volatile("s_waitcnt lgkmcnt(0)" ::: "memory");
    __builtin_amdgcn_s_barrier();
    __builtin_amdgcn_sched_barrier(0);
}

__global__ __launch_bounds__(512) void lowrank_rnn_kernel(
    const float* __restrict__ input,   // (B,T,I)
    const float* __restrict__ noise,   // (B,T,H)
    const float* __restrict__ wi,      // (I,H)
    const float* __restrict__ si,      // (I,)
    const float* __restrict__ m,       // (H,R)
    const float* __restrict__ n,       // (H,R)
    const float* __restrict__ wo,      // (H,O=1)
    const float* __restrict__ so,      // (1,)
    const float* __restrict__ h0,      // (H,)
    float* __restrict__ out)           // [output (B,T,1) | traj (B,T+1,H)]
{
    const int b    = blockIdx.x;
    const int j    = threadIdx.x;      // hidden index
    const int wave = j >> 6;
    const int lane = j & 63;

    __shared__ float  xs[T_ * I_];     // 12 KB: this batch's input sequence
    __shared__ float  os[T_];          // 4 KB: per-step outputs, flushed at end
    __shared__ float4 part[2][8];      // double-buffered per-wave partials

    // Stage x[b] into LDS (coalesced).
    for (int idx = j; idx < T_ * I_; idx += H_)
        xs[idx] = input[(size_t)b * T_ * I_ + idx];

    // Per-thread constants.
    float h   = h0[j];
    float n0v = n[2 * j], n1v = n[2 * j + 1];
    float m0v = m[2 * j], m1v = m[2 * j + 1];
    float wof = wo[j] * so[0];
    float w0  = si[0] * wi[j];
    float w1  = si[1] * wi[H_ + j];
    float w2  = si[2] * wi[2 * H_ + j];

    const float* zp    = noise + (size_t)b * T_ * H_ + j;
    float*       outp  = out + (size_t)b * T_;
    float*       trajp = out + (size_t)B_ * T_ + (size_t)b * (T_ + 1) * H_ + j;

    trajp[0] = h;  // trajectories[:,0,:] = h0

    // 4-deep noise prefetch pipeline (HBM latency ~900cyc; never drained
    // by the in-loop barrier, so issue-to-use distance = 4 steps).
    float z0 = zp[0];
    float z1 = zp[(size_t)1 * H_];
    float z2 = zp[(size_t)2 * H_];
    float z3 = zp[(size_t)3 * H_];

    __syncthreads();  // xs ready (full barrier once, outside the hot loop)

    float x0 = xs[0], x1 = xs[1], x2 = xs[2];

    #pragma unroll 2
    for (int t = 0; t < T_; ++t) {
        float r  = tanhf(h);
        float p0 = r * n0v, p1 = r * n1v, p2 = r * wof;
        wave_reduce3(p0, p1, p2);
        if (lane == 63) part[t & 1][wave] = make_float4(p0, p1, p2, 0.f);

        // Off-critical-path work while reduction partials settle.
        float zval = z0;
        float xw   = x0 * w0 + x1 * w1 + x2 * w2;
        float base = 0.8f * h + NOISE_STD * zval + ALPHA * xw;

        // Shift prefetch pipeline (clamped index: branch-free, tail re-reads last).
        z0 = z1; z1 = z2; z2 = z3;
        int tz = (t + 4 < T_) ? (t + 4) : (T_ - 1);
        z3 = zp[(size_t)tz * H_];
        int tx = (t + 1 < T_) ? (t + 1) : (T_ - 1);
        x0 = xs[tx * 3]; x1 = xs[tx * 3 + 1]; x2 = xs[tx * 3 + 2];

        barrier_lds_only();  // partials visible; vmem stays in flight

        float4 q0 = part[t & 1][0], q1 = part[t & 1][1];
        float4 q2 = part[t & 1][2], q3 = part[t & 1][3];
        float4 q4 = part[t & 1][4], q5 = part[t & 1][5];
        float4 q6 = part[t & 1][6], q7 = part[t & 1][7];
        float a0 = ((q0.x + q1.x) + (q2.x + q3.x)) + ((q4.x + q5.x) + (q6.x + q7.x));
        float a1 = ((q0.y + q1.y) + (q2.y + q3.y)) + ((q4.y + q5.y) + (q6.y + q7.y));
        float o  = ((q0.z + q1.z) + (q2.z + q3.z)) + ((q4.z + q5.z) + (q6.z + q7.z));

        // out_{t-1} = tanh(h_t)·wo_full (r of this step) — LDS, flushed at end.
        if (t > 0 && j == 0) os[t - 1] = o;

        h = base + ALPHA * (a0 * m0v + a1 * m1v);
        __builtin_nontemporal_store(h, &trajp[(size_t)(t + 1) * H_]);
    }

    // Final output: out_{T-1} = tanh(h_T)·wo_full
    {
        float r  = tanhf(h);
        float p2 = r * wof;
        p2 = dpp_add<0x111>(p2); p2 = dpp_add<0x112>(p2);
        p2 = dpp_add<0x114>(p2); p2 = dpp_add<0x118>(p2);
        p2 = dpp_add<0x142>(p2); p2 = dpp_add<0x143>(p2);
        if (lane == 63) part[0][wave] = make_float4(0.f, 0.f, p2, 0.f);
        __syncthreads();
        if (j == 0) {
            float o = 0.f;
            for (int w = 0; w < 8; ++w) o += part[0][w].z;
            os[T_ - 1] = o;
        }
    }

    // Coalesced flush of outputs.
    __syncthreads();
    for (int idx = j; idx < T_; idx += H_)
        outp[idx] = os[idx];
}

extern "C" void kernel_launch(void* const* d_in, const int* in_sizes, int n_in,
                              void* d_out, int out_size, void* d_ws, size_t ws_size,
                              hipStream_t stream) {
    const float* input = (const float*)d_in[0];
    const float* noise = (const float*)d_in[1];
    const float* wi    = (const float*)d_in[2];
    const float* si    = (const float*)d_in[3];
    const float* m     = (const float*)d_in[4];
    const float* n     = (const float*)d_in[5];
    const float* wo    = (const float*)d_in[6];
    const float* so    = (const float*)d_in[7];
    const float* h0    = (const float*)d_in[8];
    float* out = (float*)d_out;

    hipLaunchKernelGGL(lowrank_rnn_kernel, dim3(B_), dim3(H_), 0, stream,
                       input, noise, wi, si, m, n, wo, so, h0, out);
}

// Round 4
// 393.478 us; speedup vs baseline: 1.4459x; 1.2513x over previous
//
#include <hip/hip_runtime.h>

#define B_ 128
#define T_ 1000
#define I_ 3
#define H_ 512

typedef float vfloat4 __attribute__((ext_vector_type(4)));

// DPP-based add of a lane-shifted copy: x += dpp_mov(x, CTRL).
// row_shr:N = 0x110|N, row_bcast:15 = 0x142, row_bcast:31 = 0x143.
template <int CTRL>
__device__ __forceinline__ float dpp_add(float x) {
    int moved = __builtin_amdgcn_update_dpp(0, __float_as_int(x), CTRL, 0xf, 0xf, true);
    return x + __int_as_float(moved);
}

// Full wave64 sum of 3 values simultaneously (interleaved: 3-way ILP covers
// the DPP dependency latency). Totals valid in lane 63.
__device__ __forceinline__ void wave_reduce3(float& p0, float& p1, float& p2) {
    p0 = dpp_add<0x111>(p0); p1 = dpp_add<0x111>(p1); p2 = dpp_add<0x111>(p2);
    p0 = dpp_add<0x112>(p0); p1 = dpp_add<0x112>(p1); p2 = dpp_add<0x112>(p2);
    p0 = dpp_add<0x114>(p0); p1 = dpp_add<0x114>(p1); p2 = dpp_add<0x114>(p2);
    p0 = dpp_add<0x118>(p0); p1 = dpp_add<0x118>(p1); p2 = dpp_add<0x118>(p2);
    p0 = dpp_add<0x142>(p0); p1 = dpp_add<0x142>(p1); p2 = dpp_add<0x142>(p2);
    p0 = dpp_add<0x143>(p0); p1 = dpp_add<0x143>(p1); p2 = dpp_add<0x143>(p2);
}

// tanh(x) = 1 - 2/(e^{2x}+1), via hardware exp2 + rcp (~2-3 ulp).
// Saturates gracefully: E->inf => 1, E->0 => -1. 5 VALU ops vs ~20 for libm.
__device__ __forceinline__ float fast_tanh(float x) {
    float E = __builtin_amdgcn_exp2f(x * 2.885390081777927f);  // e^(2x)
    float r = __builtin_amdgcn_rcpf(E + 1.0f);
    return __builtin_fmaf(-2.0f, r, 1.0f);
}

__global__ __launch_bounds__(64) void lowrank_rnn_kernel(
    const float* __restrict__ input,   // (B,T,I)
    const float* __restrict__ noise,   // (B,T,H)
    const float* __restrict__ wi,      // (I,H)
    const float* __restrict__ si,      // (I,)
    const float* __restrict__ m,       // (H,R)
    const float* __restrict__ n,       // (H,R)
    const float* __restrict__ wo,      // (H,O=1)
    const float* __restrict__ so,      // (1,)
    const float* __restrict__ h0,      // (H,)
    float* __restrict__ out)           // [output (B,T,1) | traj (B,T+1,H)]
{
    const int b    = blockIdx.x;   // one batch element per 64-thread block (1 wave)
    const int lane = threadIdx.x;  // 0..63
    const int j0   = lane * 8;     // this lane owns hidden units j0..j0+7

    __shared__ float os[T_ + 1];   // per-step scalar outputs; os[t] = out[t-1]

    // ---- per-lane constants (0.2 = ALPHA folded into m and wi; so into wo) ----
    float h[8], n0[8], n1[8], m0S[8], m1S[8], wof[8], wS0[8], wS1[8], wS2[8];

    {
        const float so0 = so[0];
        const float* nb = n + 2 * j0;   // 16 consecutive floats: (n0,n1) pairs
        const float* mb = m + 2 * j0;
        #pragma unroll
        for (int q = 0; q < 4; ++q) {
            vfloat4 vn = *(const vfloat4*)(nb + 4 * q);
            n0[2*q] = vn.x; n1[2*q] = vn.y; n0[2*q+1] = vn.z; n1[2*q+1] = vn.w;
            vfloat4 vm = *(const vfloat4*)(mb + 4 * q);
            m0S[2*q] = 0.2f * vm.x; m1S[2*q] = 0.2f * vm.y;
            m0S[2*q+1] = 0.2f * vm.z; m1S[2*q+1] = 0.2f * vm.w;
        }
        #pragma unroll
        for (int q = 0; q < 2; ++q) {
            vfloat4 vw = *(const vfloat4*)(wo + j0 + 4 * q);
            wof[4*q] = vw.x * so0; wof[4*q+1] = vw.y * so0;
            wof[4*q+2] = vw.z * so0; wof[4*q+3] = vw.w * so0;
            vfloat4 vh = *(const vfloat4*)(h0 + j0 + 4 * q);
            h[4*q] = vh.x; h[4*q+1] = vh.y; h[4*q+2] = vh.z; h[4*q+3] = vh.w;
        }
        #pragma unroll
        for (int i = 0; i < 3; ++i) {
            float s = 0.2f * si[i];
            float* dst = (i == 0) ? wS0 : (i == 1) ? wS1 : wS2;
            #pragma unroll
            for (int q = 0; q < 2; ++q) {
                vfloat4 vw = *(const vfloat4*)(wi + i * H_ + j0 + 4 * q);
                dst[4*q] = vw.x * s; dst[4*q+1] = vw.y * s;
                dst[4*q+2] = vw.z * s; dst[4*q+3] = vw.w * s;
            }
        }
    }

    float* trajBase = out + (size_t)B_ * T_ + (size_t)b * (T_ + 1) * H_;
    // trajectories[:,0,:] = h0
    {
        vfloat4 lo = {h[0], h[1], h[2], h[3]};
        vfloat4 hi = {h[4], h[5], h[6], h[7]};
        *(vfloat4*)(trajBase + j0)     = lo;
        *(vfloat4*)(trajBase + j0 + 4) = hi;
    }

    const float* zrow = noise + (size_t)b * T_ * H_;
    const float* xb   = input + (size_t)b * T_ * I_;   // uniform addr -> s_load

    auto LDZ = [&](int t, vfloat4& lo, vfloat4& hi) {
        const float* p = zrow + (size_t)t * H_ + j0;
        lo = *(const vfloat4*)p;
        hi = *(const vfloat4*)(p + 4);
    };

    // One recurrence step. All work per-lane except the DPP reduce + readlane.
    auto STEP = [&](int t, vfloat4 zlo, vfloat4 zhi, float cx0, float cx1, float cx2) {
        float r[8];
        #pragma unroll
        for (int k = 0; k < 8; ++k) r[k] = fast_tanh(h[k]);

        float p0 = r[0] * n0[0], p1 = r[0] * n1[0], p2 = r[0] * wof[0];
        #pragma unroll
        for (int k = 1; k < 8; ++k) {
            p0 = __builtin_fmaf(r[k], n0[k], p0);
            p1 = __builtin_fmaf(r[k], n1[k], p1);
            p2 = __builtin_fmaf(r[k], wof[k], p2);
        }
        wave_reduce3(p0, p1, p2);

        // Independent of the reduction: fills issue slots while DPP chain runs.
        float zz[8] = {zlo.x, zlo.y, zlo.z, zlo.w, zhi.x, zhi.y, zhi.z, zhi.w};
        float base[8];
        #pragma unroll
        for (int k = 0; k < 8; ++k) {
            float xw = __builtin_fmaf(cx0, wS0[k],
                       __builtin_fmaf(cx1, wS1[k], cx2 * wS2[k]));
            base[k] = __builtin_fmaf(h[k], 0.8f,
                      __builtin_fmaf(zz[k], 0.05f, xw));
        }

        float a0 = __int_as_float(__builtin_amdgcn_readlane(__float_as_int(p0), 63));
        float a1 = __int_as_float(__builtin_amdgcn_readlane(__float_as_int(p1), 63));
        if (lane == 63) os[t] = p2;   // out[t-1] = tanh(h_t)·wo_full

        #pragma unroll
        for (int k = 0; k < 8; ++k)
            h[k] = __builtin_fmaf(a0, m0S[k], __builtin_fmaf(a1, m1S[k], base[k]));

        float* tr = trajBase + (size_t)(t + 1) * H_ + j0;
        vfloat4 lo = {h[0], h[1], h[2], h[3]};
        vfloat4 hi = {h[4], h[5], h[6], h[7]};
        __builtin_nontemporal_store(lo, (vfloat4*)tr);
        __builtin_nontemporal_store(hi, (vfloat4*)(tr + 4));
    };

    // 6-row noise pipeline: issue-to-use = 2 iterations = 4 steps (~1600 cyc).
    vfloat4 zAlo, zAhi, zBlo, zBhi, zClo, zChi, zDlo, zDhi;
    LDZ(0, zAlo, zAhi); LDZ(1, zBlo, zBhi);
    LDZ(2, zClo, zChi); LDZ(3, zDlo, zDhi);
    float cx0 = xb[0], cx1 = xb[1], cx2 = xb[2];

    for (int t = 0; t < T_; t += 2) {
        vfloat4 zElo, zEhi, zFlo, zFhi;
        int t4 = (t + 4 < T_) ? t + 4 : T_ - 1;   // clamp: stay in-buffer
        int t5 = (t + 5 < T_) ? t + 5 : T_ - 1;
        LDZ(t4, zElo, zEhi); LDZ(t5, zFlo, zFhi);

        float nx0 = xb[3*(t+1)], nx1 = xb[3*(t+1)+1], nx2 = xb[3*(t+1)+2];
        STEP(t, zAlo, zAhi, cx0, cx1, cx2);

        int t2 = (t + 2 < T_) ? t + 2 : T_ - 1;
        float mx0 = xb[3*t2], mx1 = xb[3*t2+1], mx2 = xb[3*t2+2];
        STEP(t + 1, zBlo, zBhi, nx0, nx1, nx2);

        cx0 = mx0; cx1 = mx1; cx2 = mx2;
        zAlo = zClo; zAhi = zChi; zBlo = zDlo; zBhi = zDhi;
        zClo = zElo; zChi = zEhi; zDlo = zFlo; zDhi = zFhi;
    }

    // Final output: out[T-1] = tanh(h_T)·wo_full
    {
        float r[8];
        #pragma unroll
        for (int k = 0; k < 8; ++k) r[k] = fast_tanh(h[k]);
        float p2 = r[0] * wof[0];
        #pragma unroll
        for (int k = 1; k < 8; ++k) p2 = __builtin_fmaf(r[k], wof[k], p2);
        p2 = dpp_add<0x111>(p2); p2 = dpp_add<0x112>(p2);
        p2 = dpp_add<0x114>(p2); p2 = dpp_add<0x118>(p2);
        p2 = dpp_add<0x142>(p2); p2 = dpp_add<0x143>(p2);
        if (lane == 63) os[T_] = p2;
    }

    // Single wave: no barrier needed; compiler orders ds ops via lgkmcnt.
    float* outp = out + (size_t)b * T_;
    for (int idx = lane; idx < T_; idx += 64)
        outp[idx] = os[idx + 1];
}

extern "C" void kernel_launch(void* const* d_in, const int* in_sizes, int n_in,
                              void* d_out, int out_size, void* d_ws, size_t ws_size,
                              hipStream_t stream) {
    const float* input = (const float*)d_in[0];
    const float* noise = (const float*)d_in[1];
    const float* wi    = (const float*)d_in[2];
    const float* si    = (const float*)d_in[3];
    const float* m     = (const float*)d_in[4];
    const float* n     = (const float*)d_in[5];
    const float* wo    = (const float*)d_in[6];
    const float* so    = (const float*)d_in[7];
    const float* h0    = (const float*)d_in[8];
    float* out = (float*)d_out;

    hipLaunchKernelGGL(lowrank_rnn_kernel, dim3(B_), dim3(64), 0, stream,
                       input, noise, wi, si, m, n, wo, so, h0, out);
}

// Round 5
// 338.996 us; speedup vs baseline: 1.6782x; 1.1607x over previous
//
#include <hip/hip_runtime.h>

#define B_ 128
#define T_ 1000
#define I_ 3
#define H_ 512
#define RING 16      // noise prefetch depth in steps (register ring)

typedef float vfloat4 __attribute__((ext_vector_type(4)));

// DPP-based add of a lane-shifted copy: x += dpp_mov(x, CTRL).
// row_shr:N = 0x110|N, row_bcast:15 = 0x142, row_bcast:31 = 0x143.
template <int CTRL>
__device__ __forceinline__ float dpp_add(float x) {
    int moved = __builtin_amdgcn_update_dpp(0, __float_as_int(x), CTRL, 0xf, 0xf, true);
    return x + __int_as_float(moved);
}

// Full wave64 sum of 3 values simultaneously (interleaved: 3-way ILP covers
// the DPP dependency latency). Totals valid in lane 63.
__device__ __forceinline__ void wave_reduce3(float& p0, float& p1, float& p2) {
    p0 = dpp_add<0x111>(p0); p1 = dpp_add<0x111>(p1); p2 = dpp_add<0x111>(p2);
    p0 = dpp_add<0x112>(p0); p1 = dpp_add<0x112>(p1); p2 = dpp_add<0x112>(p2);
    p0 = dpp_add<0x114>(p0); p1 = dpp_add<0x114>(p1); p2 = dpp_add<0x114>(p2);
    p0 = dpp_add<0x118>(p0); p1 = dpp_add<0x118>(p1); p2 = dpp_add<0x118>(p2);
    p0 = dpp_add<0x142>(p0); p1 = dpp_add<0x142>(p1); p2 = dpp_add<0x142>(p2);
    p0 = dpp_add<0x143>(p0); p1 = dpp_add<0x143>(p1); p2 = dpp_add<0x143>(p2);
}

// tanh(x) = 1 - 2/(e^{2x}+1), via hardware exp2 + rcp (~2-3 ulp).
__device__ __forceinline__ float fast_tanh(float x) {
    float E = __builtin_amdgcn_exp2f(x * 2.885390081777927f);  // e^(2x)
    float r = __builtin_amdgcn_rcpf(E + 1.0f);
    return __builtin_fmaf(-2.0f, r, 1.0f);
}

__global__ __launch_bounds__(64, 1) void lowrank_rnn_kernel(
    const float* __restrict__ input,   // (B,T,I)
    const float* __restrict__ noise,   // (B,T,H)
    const float* __restrict__ wi,      // (I,H)
    const float* __restrict__ si,      // (I,)
    const float* __restrict__ m,       // (H,R)
    const float* __restrict__ n,       // (H,R)
    const float* __restrict__ wo,      // (H,O=1)
    const float* __restrict__ so,      // (1,)
    const float* __restrict__ h0,      // (H,)
    float* __restrict__ out)           // [output (B,T,1) | traj (B,T+1,H)]
{
    const int b    = blockIdx.x;   // one batch element per 64-thread block (1 wave)
    const int lane = threadIdx.x;  // 0..63
    const int j0   = lane * 8;     // this lane owns hidden units j0..j0+7

    __shared__ float os[T_ + 1];   // per-step scalar outputs; os[t] = out[t-1]

    // ---- per-lane constants (0.2 = ALPHA folded into m and wi; so into wo) ----
    float h[8], n0[8], n1[8], m0S[8], m1S[8], wof[8], wS0[8], wS1[8], wS2[8];

    {
        const float so0 = so[0];
        const float* nb = n + 2 * j0;   // 16 consecutive floats: (n0,n1) pairs
        const float* mb = m + 2 * j0;
        #pragma unroll
        for (int q = 0; q < 4; ++q) {
            vfloat4 vn = *(const vfloat4*)(nb + 4 * q);
            n0[2*q] = vn.x; n1[2*q] = vn.y; n0[2*q+1] = vn.z; n1[2*q+1] = vn.w;
            vfloat4 vm = *(const vfloat4*)(mb + 4 * q);
            m0S[2*q] = 0.2f * vm.x; m1S[2*q] = 0.2f * vm.y;
            m0S[2*q+1] = 0.2f * vm.z; m1S[2*q+1] = 0.2f * vm.w;
        }
        #pragma unroll
        for (int q = 0; q < 2; ++q) {
            vfloat4 vw = *(const vfloat4*)(wo + j0 + 4 * q);
            wof[4*q] = vw.x * so0; wof[4*q+1] = vw.y * so0;
            wof[4*q+2] = vw.z * so0; wof[4*q+3] = vw.w * so0;
            vfloat4 vh = *(const vfloat4*)(h0 + j0 + 4 * q);
            h[4*q] = vh.x; h[4*q+1] = vh.y; h[4*q+2] = vh.z; h[4*q+3] = vh.w;
        }
        #pragma unroll
        for (int i = 0; i < 3; ++i) {
            float s = 0.2f * si[i];
            float* dst = (i == 0) ? wS0 : (i == 1) ? wS1 : wS2;
            #pragma unroll
            for (int q = 0; q < 2; ++q) {
                vfloat4 vw = *(const vfloat4*)(wi + i * H_ + j0 + 4 * q);
                dst[4*q] = vw.x * s; dst[4*q+1] = vw.y * s;
                dst[4*q+2] = vw.z * s; dst[4*q+3] = vw.w * s;
            }
        }
    }

    float* trajBase = out + (size_t)B_ * T_ + (size_t)b * (T_ + 1) * H_;
    {   // trajectories[:,0,:] = h0
        vfloat4 lo = {h[0], h[1], h[2], h[3]};
        vfloat4 hi = {h[4], h[5], h[6], h[7]};
        *(vfloat4*)(trajBase + j0)     = lo;
        *(vfloat4*)(trajBase + j0 + 4) = hi;
    }

    const float* zrow = noise + (size_t)b * T_ * H_ + j0;
    const float* xb   = input + (size_t)b * T_ * I_;   // wave-uniform -> s_load

    // Noise register ring: 16 rows x 8 floats = 128 VGPR. Indexed ONLY with
    // compile-time constants (unrolled loops) so it stays in registers.
    vfloat4 zlo[RING], zhi[RING];

    #pragma unroll
    for (int s = 0; s < RING; ++s) {
        const float* p = zrow + (size_t)s * H_;
        zlo[s] = *(const vfloat4*)p;
        zhi[s] = *(const vfloat4*)(p + 4);
    }

    // One step: consume ring slot (by reference), reload it RING steps ahead.
    auto STEP = [&](int t, vfloat4& slo, vfloat4& shi,
                    float cx0, float cx1, float cx2, bool reload) {
        vfloat4 zl = slo, zh = shi;
        if (reload) {   // issue loads FIRST: they precede this step's stores in vmcnt order
            int tz = (t + RING < T_) ? t + RING : T_ - 1;
            const float* p = zrow + (size_t)tz * H_;
            slo = *(const vfloat4*)p;
            shi = *(const vfloat4*)(p + 4);
        }

        float r[8];
        #pragma unroll
        for (int k = 0; k < 8; ++k) r[k] = fast_tanh(h[k]);

        float p0 = r[0] * n0[0], p1 = r[0] * n1[0], p2 = r[0] * wof[0];
        #pragma unroll
        for (int k = 1; k < 8; ++k) {
            p0 = __builtin_fmaf(r[k], n0[k], p0);
            p1 = __builtin_fmaf(r[k], n1[k], p1);
            p2 = __builtin_fmaf(r[k], wof[k], p2);
        }
        wave_reduce3(p0, p1, p2);

        // Independent of the reduction: fills issue slots while DPP chain runs.
        float zz[8] = {zl.x, zl.y, zl.z, zl.w, zh.x, zh.y, zh.z, zh.w};
        float base[8];
        #pragma unroll
        for (int k = 0; k < 8; ++k) {
            float xw = __builtin_fmaf(cx0, wS0[k],
                       __builtin_fmaf(cx1, wS1[k], cx2 * wS2[k]));
            base[k] = __builtin_fmaf(h[k], 0.8f,
                      __builtin_fmaf(zz[k], 0.05f, xw));
        }

        float a0 = __int_as_float(__builtin_amdgcn_readlane(__float_as_int(p0), 63));
        float a1 = __int_as_float(__builtin_amdgcn_readlane(__float_as_int(p1), 63));
        if (lane == 63) os[t] = p2;   // out[t-1] = tanh(h_t)·wo_full

        #pragma unroll
        for (int k = 0; k < 8; ++k)
            h[k] = __builtin_fmaf(a0, m0S[k], __builtin_fmaf(a1, m1S[k], base[k]));

        float* tr = trajBase + (size_t)(t + 1) * H_ + j0;
        vfloat4 lo = {h[0], h[1], h[2], h[3]};
        vfloat4 hi = {h[4], h[5], h[6], h[7]};
        *(vfloat4*)tr       = lo;   // plain store: fast L2 ack, stays off vmcnt tail
        *(vfloat4*)(tr + 4) = hi;
    };

    // Main: 62 super-iterations x 16 steps (t = 0..991), slot = t % 16 = s.
    for (int tt = 0; tt < T_ - 8; tt += RING) {
        // Hoist this body's x values (wave-uniform s_loads, lgkmcnt counter —
        // independent of the vmcnt load/store stream).
        float xv0[RING], xv1[RING], xv2[RING];
        #pragma unroll
        for (int s = 0; s < RING; ++s) {
            xv0[s] = xb[3 * (tt + s) + 0];
            xv1[s] = xb[3 * (tt + s) + 1];
            xv2[s] = xb[3 * (tt + s) + 2];
        }
        #pragma unroll
        for (int s = 0; s < RING; ++s)
            STEP(tt + s, zlo[s], zhi[s], xv0[s], xv1[s], xv2[s], true);
    }

    // Tail: steps 992..999 consume slots 0..7 (loaded with rows 992..999), no reload.
    {
        const int tt = T_ - 8;
        #pragma unroll
        for (int s = 0; s < 8; ++s) {
            float cx0 = xb[3 * (tt + s) + 0];
            float cx1 = xb[3 * (tt + s) + 1];
            float cx2 = xb[3 * (tt + s) + 2];
            STEP(tt + s, zlo[s], zhi[s], cx0, cx1, cx2, false);
        }
    }

    // Final output: out[T-1] = tanh(h_T)·wo_full
    {
        float r[8];
        #pragma unroll
        for (int k = 0; k < 8; ++k) r[k] = fast_tanh(h[k]);
        float p2 = r[0] * wof[0];
        #pragma unroll
        for (int k = 1; k < 8; ++k) p2 = __builtin_fmaf(r[k], wof[k], p2);
        p2 = dpp_add<0x111>(p2); p2 = dpp_add<0x112>(p2);
        p2 = dpp_add<0x114>(p2); p2 = dpp_add<0x118>(p2);
        p2 = dpp_add<0x142>(p2); p2 = dpp_add<0x143>(p2);
        if (lane == 63) os[T_] = p2;
    }

    // Single wave: no barrier needed; lgkmcnt orders the ds ops.
    float* outp = out + (size_t)b * T_;
    for (int idx = lane; idx < T_; idx += 64)
        outp[idx] = os[idx + 1];
}

extern "C" void kernel_launch(void* const* d_in, const int* in_sizes, int n_in,
                              void* d_out, int out_size, void* d_ws, size_t ws_size,
                              hipStream_t stream) {
    const float* input = (const float*)d_in[0];
    const float* noise = (const float*)d_in[1];
    const float* wi    = (const float*)d_in[2];
    const float* si    = (const float*)d_in[3];
    const float* m     = (const float*)d_in[4];
    const float* n     = (const float*)d_in[5];
    const float* wo    = (const float*)d_in[6];
    const float* so    = (const float*)d_in[7];
    const float* h0    = (const float*)d_in[8];
    float* out = (float*)d_out;

    hipLaunchKernelGGL(lowrank_rnn_kernel, dim3(B_), dim3(64), 0, stream,
                       input, noise, wi, si, m, n, wo, so, h0, out);
}